// Round 1
// baseline (275.972 us; speedup 1.0000x reference)
//
#include <hip/hip_runtime.h>

typedef unsigned short u16;
typedef unsigned int   u32;
typedef __attribute__((ext_vector_type(8))) short bf16x8;
typedef __attribute__((ext_vector_type(4))) float f32x4;

#define SEQ 1024
#define BSZ 8
#define EMB 1024
#define NH  16
#define DH  64
// M rows of the flattened (S,B) GEMMs
#define MROWS (SEQ*BSZ)

__device__ __forceinline__ u16 f2bf(float f) {
    u32 u = __float_as_uint(f);
    u32 r = u + 0x7FFFu + ((u >> 16) & 1u);   // round-to-nearest-even
    return (u16)(r >> 16);
}

// ---------------- convert x (fp32) -> xb (bf16) ----------------
__global__ __launch_bounds__(256) void cvt_x_k(const float* __restrict__ x,
                                               u16* __restrict__ xb) {
    size_t i = ((size_t)blockIdx.x * 256 + threadIdx.x) * 8;
    float4 a = *reinterpret_cast<const float4*>(x + i);
    float4 b = *reinterpret_cast<const float4*>(x + i + 4);
    union { u16 u[8]; uint4 v; } o;
    o.u[0]=f2bf(a.x); o.u[1]=f2bf(a.y); o.u[2]=f2bf(a.z); o.u[3]=f2bf(a.w);
    o.u[4]=f2bf(b.x); o.u[5]=f2bf(b.y); o.u[6]=f2bf(b.z); o.u[7]=f2bf(b.w);
    *reinterpret_cast<uint4*>(xb + i) = o.v;
}

// ------- convert + transpose weights: w (K=1024,N=1024) fp32 -> wT (N,K) bf16 -------
__global__ __launch_bounds__(256) void cvt_w_k(const float* __restrict__ w0, const float* __restrict__ w1,
                                               const float* __restrict__ w2, const float* __restrict__ w3,
                                               u16* __restrict__ wT) {
    int id  = blockIdx.x * 256 + threadIdx.x;     // 2048 blocks -> 524288 threads
    int wi  = id >> 17;                           // 131072 chunks per matrix
    int rem = id & 131071;
    int kc  = rem >> 10;                          // 0..127 (k-chunk of 8)
    int n   = rem & 1023;                         // coalesced over lanes
    const float* src = (wi==0) ? w0 : (wi==1) ? w1 : (wi==2) ? w2 : w3;
    union { u16 u[8]; uint4 v; } o;
    #pragma unroll
    for (int i = 0; i < 8; ++i) o.u[i] = f2bf(src[(size_t)(kc*8+i)*1024 + n]);
    *reinterpret_cast<uint4*>(wT + (size_t)wi*1048576 + (size_t)n*1024 + kc*8) = o.v;
}

// ---------------- bf16 GEMM, C = A(M,K) * BT(N,K)^T ----------------
// MODE 0: proj. z=blockIdx.z selects wq/wk/wv; epilogue writes head layout
//         qh/kh/vh[(b*NH+h)*SEQ + s][d], q scaled, v += x residual.
// MODE 1: out-proj. epilogue: out[m][n] = acc + bias[n] (fp32).
template<int MODE>
__global__ __launch_bounds__(256) void gemm_bt(
    const u16* __restrict__ A, const u16* __restrict__ BT,
    const float* __restrict__ xres, const float* __restrict__ bias,
    u16* __restrict__ qh, u16* __restrict__ kh, u16* __restrict__ vh,
    float* __restrict__ outp)
{
    __shared__ u16 As[2][128*32];
    __shared__ u16 Bs[2][128*32];

    const int tid  = threadIdx.x;
    const int lane = tid & 63;
    const int wv   = tid >> 6;
    const int wm   = wv >> 1, wn = wv & 1;
    const int mBase = blockIdx.y * 128;
    const int nBase = blockIdx.x * 128;
    const int z = (MODE == 0) ? blockIdx.z : 0;
    const u16* Bm = BT + (size_t)z * (1024*1024);

    // staging: 512 chunks of 16B per tile; thread owns chunk tid and tid+256
    const int r0  = tid >> 2;          // row 0..63
    const int cb0 = tid & 3;           // 16B chunk within 64B row
    const u16* Ap0 = A  + (size_t)(mBase + r0)      * 1024 + cb0*8;
    const u16* Ap1 = A  + (size_t)(mBase + r0 + 64) * 1024 + cb0*8;
    const u16* Bp0 = Bm + (size_t)(nBase + r0)      * 1024 + cb0*8;
    const u16* Bp1 = Bm + (size_t)(nBase + r0 + 64) * 1024 + cb0*8;
    const int lo0 = r0*32 + cb0*8;
    const int lo1 = (r0+64)*32 + cb0*8;

    f32x4 acc[4][4];
    #pragma unroll
    for (int i = 0; i < 4; ++i)
        #pragma unroll
        for (int j = 0; j < 4; ++j) acc[i][j] = (f32x4){0.f,0.f,0.f,0.f};

    uint4 ra0 = *reinterpret_cast<const uint4*>(Ap0);
    uint4 ra1 = *reinterpret_cast<const uint4*>(Ap1);
    uint4 rb0 = *reinterpret_cast<const uint4*>(Bp0);
    uint4 rb1 = *reinterpret_cast<const uint4*>(Bp1);
    *reinterpret_cast<uint4*>(&As[0][lo0]) = ra0;
    *reinterpret_cast<uint4*>(&As[0][lo1]) = ra1;
    *reinterpret_cast<uint4*>(&Bs[0][lo0]) = rb0;
    *reinterpret_cast<uint4*>(&Bs[0][lo1]) = rb1;

    const int NT = 1024 / 32;
    int cur = 0;
    const int arow = wm*64 + (lane & 15);
    const int brow = wn*64 + (lane & 15);
    const int kcol = (lane >> 4) * 8;

    for (int kt = 0; kt < NT; ++kt) {
        __syncthreads();
        if (kt + 1 < NT) {
            const int ko = (kt + 1) * 32;
            ra0 = *reinterpret_cast<const uint4*>(Ap0 + ko);
            ra1 = *reinterpret_cast<const uint4*>(Ap1 + ko);
            rb0 = *reinterpret_cast<const uint4*>(Bp0 + ko);
            rb1 = *reinterpret_cast<const uint4*>(Bp1 + ko);
        }
        bf16x8 af[4], bf[4];
        #pragma unroll
        for (int f = 0; f < 4; ++f)
            af[f] = *reinterpret_cast<const bf16x8*>(&As[cur][(arow + f*16)*32 + kcol]);
        #pragma unroll
        for (int f = 0; f < 4; ++f)
            bf[f] = *reinterpret_cast<const bf16x8*>(&Bs[cur][(brow + f*16)*32 + kcol]);
        #pragma unroll
        for (int i = 0; i < 4; ++i)
            #pragma unroll
            for (int j = 0; j < 4; ++j)
                acc[i][j] = __builtin_amdgcn_mfma_f32_16x16x32_bf16(af[i], bf[j], acc[i][j], 0, 0, 0);
        if (kt + 1 < NT) {
            __syncthreads();
            const int nb = cur ^ 1;
            *reinterpret_cast<uint4*>(&As[nb][lo0]) = ra0;
            *reinterpret_cast<uint4*>(&As[nb][lo1]) = ra1;
            *reinterpret_cast<uint4*>(&Bs[nb][lo0]) = rb0;
            *reinterpret_cast<uint4*>(&Bs[nb][lo1]) = rb1;
            cur = nb;
        }
    }

    // epilogue: C layout col=lane&15, row=(lane>>4)*4+reg
    const int rbase = (lane >> 4) * 4;
    const int cbase = lane & 15;
    #pragma unroll
    for (int i = 0; i < 4; ++i) {
        #pragma unroll
        for (int j = 0; j < 4; ++j) {
            #pragma unroll
            for (int r = 0; r < 4; ++r) {
                const int m = mBase + wm*64 + i*16 + rbase + r;
                const int n = nBase + wn*64 + j*16 + cbase;
                const float v = acc[i][j][r];
                if (MODE == 0) {
                    const int s = m >> 3, bb = m & 7;
                    const int h = n >> 6, d  = n & 63;
                    const size_t oidx = ((size_t)(bb*NH + h)*SEQ + s)*DH + d;
                    if (z == 0)      qh[oidx] = f2bf(v * 0.125f);
                    else if (z == 1) kh[oidx] = f2bf(v);
                    else             vh[oidx] = f2bf(v + xres[(size_t)m*1024 + n]);
                } else {
                    outp[(size_t)m*1024 + n] = v + bias[n];
                }
            }
        }
    }
}

// ---------------- flash attention: one (bh, 64-q-row tile) per block ----------------
__global__ __launch_bounds__(256) void attn_k(
    const u16* __restrict__ qh, const u16* __restrict__ kh,
    const u16* __restrict__ vh, const float* __restrict__ mask,
    u16* __restrict__ ctx)
{
    __shared__ u16 Kl[64*64];   // [key][d], 16B chunks XOR-swizzled by (key&7)<<4
    __shared__ u16 Vt[64*64];   // [d][key], swizzled by (d&7)<<4
    __shared__ u16 Pl[64*64];   // [q][key], swizzled by (q&7)<<4

    const int tid  = threadIdx.x;
    const int lane = tid & 63;
    const int wv   = tid >> 6;
    const int bh = blockIdx.y;
    const int b  = bh >> 4;
    const int h  = bh & 15;
    const int qbase = blockIdx.x * 64;
    const size_t bhOff = (size_t)bh * SEQ * DH;

    // Q fragments (A-operand): row = lane&15, k = kk*32 + (lane>>4)*8 + i
    bf16x8 aq[2];
    const int qrow = qbase + wv*16 + (lane & 15);
    #pragma unroll
    for (int kk = 0; kk < 2; ++kk)
        aq[kk] = *reinterpret_cast<const bf16x8*>(qh + bhOff + (size_t)qrow*DH + kk*32 + (lane >> 4)*8);

    f32x4 o[4];
    #pragma unroll
    for (int f = 0; f < 4; ++f) o[f] = (f32x4){0.f,0.f,0.f,0.f};
    float mrun[4], lrun[4];
    #pragma unroll
    for (int j = 0; j < 4; ++j) { mrun[j] = -1e30f; lrun[j] = 0.f; }

    const int kKey = tid >> 3, kDb = tid & 7;      // K staging (coalesced rows)
    const int vKey = tid & 63, vDb = tid >> 6;     // V staging (conflict-friendly transpose)

    for (int kt = 0; kt < 16; ++kt) {
        const int jb = kt * 64;
        // ---- stage K tile ----
        #pragma unroll
        for (int c = 0; c < 2; ++c) {
            const int key = kKey + 32*c;
            uint4 val = *reinterpret_cast<const uint4*>(kh + bhOff + (size_t)(jb + key)*DH + kDb*8);
            const int off = (key*128 + kDb*16) ^ ((key & 7) << 4);
            *reinterpret_cast<uint4*>(reinterpret_cast<char*>(Kl) + off) = val;
        }
        // ---- stage V tile transposed ----
        #pragma unroll
        for (int c = 0; c < 2; ++c) {
            const int db = vDb + 4*c;
            union { uint4 v; u16 u[8]; } val;
            val.v = *reinterpret_cast<const uint4*>(vh + bhOff + (size_t)(jb + vKey)*DH + db*8);
            #pragma unroll
            for (int i = 0; i < 8; ++i) {
                const int d = db*8 + i;                       // d&7 == i
                const int off = (d*128 + vKey*2) ^ (i << 4);
                *reinterpret_cast<u16*>(reinterpret_cast<char*>(Vt) + off) = val.u[i];
            }
        }
        __syncthreads();

        // ---- scores: S = Q * K^T ----
        f32x4 sc[4];
        #pragma unroll
        for (int fn = 0; fn < 4; ++fn) {
            sc[fn] = (f32x4){0.f,0.f,0.f,0.f};
            #pragma unroll
            for (int kk = 0; kk < 2; ++kk) {
                const int krow = fn*16 + (lane & 15);
                const int off = (krow*128 + (kk*32 + (lane >> 4)*8)*2) ^ ((krow & 7) << 4);
                bf16x8 bk = *reinterpret_cast<const bf16x8*>(reinterpret_cast<char*>(Kl) + off);
                sc[fn] = __builtin_amdgcn_mfma_f32_16x16x32_bf16(aq[kk], bk, sc[fn], 0, 0, 0);
            }
        }
        // additive key-padding mask
        #pragma unroll
        for (int fn = 0; fn < 4; ++fn) {
            const float mv = mask[(size_t)b*SEQ + jb + fn*16 + (lane & 15)];
            #pragma unroll
            for (int j = 0; j < 4; ++j) sc[fn][j] += mv;
        }
        // ---- online softmax ----
        float mx[4];
        #pragma unroll
        for (int j = 0; j < 4; ++j)
            mx[j] = fmaxf(fmaxf(sc[0][j], sc[1][j]), fmaxf(sc[2][j], sc[3][j]));
        #pragma unroll
        for (int off = 1; off < 16; off <<= 1)
            #pragma unroll
            for (int j = 0; j < 4; ++j) mx[j] = fmaxf(mx[j], __shfl_xor(mx[j], off));
        float scl[4], rs[4];
        #pragma unroll
        for (int j = 0; j < 4; ++j) {
            const float mn = fmaxf(mrun[j], mx[j]);
            scl[j] = __expf(mrun[j] - mn);
            mrun[j] = mn;
            rs[j] = 0.f;
        }
        #pragma unroll
        for (int fn = 0; fn < 4; ++fn)
            #pragma unroll
            for (int j = 0; j < 4; ++j) {
                const float p = __expf(sc[fn][j] - mrun[j]);
                sc[fn][j] = p;
                rs[j] += p;
            }
        #pragma unroll
        for (int off = 1; off < 16; off <<= 1)
            #pragma unroll
            for (int j = 0; j < 4; ++j) rs[j] += __shfl_xor(rs[j], off);
        #pragma unroll
        for (int j = 0; j < 4; ++j) lrun[j] = lrun[j]*scl[j] + rs[j];
        #pragma unroll
        for (int fn = 0; fn < 4; ++fn)
            #pragma unroll
            for (int j = 0; j < 4; ++j) o[fn][j] *= scl[j];

        // ---- P -> LDS bf16 (wave-private rows) ----
        #pragma unroll
        for (int fn = 0; fn < 4; ++fn)
            #pragma unroll
            for (int j = 0; j < 4; ++j) {
                const int q = wv*16 + (lane >> 4)*4 + j;
                const int key = fn*16 + (lane & 15);
                const int off = (q*128 + key*2) ^ ((q & 7) << 4);
                *reinterpret_cast<u16*>(reinterpret_cast<char*>(Pl) + off) = f2bf(sc[fn][j]);
            }
        // ---- O += P * V ----
        #pragma unroll
        for (int fn = 0; fn < 4; ++fn) {
            #pragma unroll
            for (int kk = 0; kk < 2; ++kk) {
                const int prow = wv*16 + (lane & 15);
                const int poff = (prow*128 + (kk*32 + (lane >> 4)*8)*2) ^ ((prow & 7) << 4);
                bf16x8 pa = *reinterpret_cast<const bf16x8*>(reinterpret_cast<char*>(Pl) + poff);
                const int vrow = fn*16 + (lane & 15);
                const int voff = (vrow*128 + (kk*32 + (lane >> 4)*8)*2) ^ ((vrow & 7) << 4);
                bf16x8 vb = *reinterpret_cast<const bf16x8*>(reinterpret_cast<char*>(Vt) + voff);
                o[fn] = __builtin_amdgcn_mfma_f32_16x16x32_bf16(pa, vb, o[fn], 0, 0, 0);
            }
        }
        __syncthreads();
    }

    // ---- epilogue: ctx[(s*B+b)][h*64+d] in bf16 ----
    #pragma unroll
    for (int j = 0; j < 4; ++j) {
        const float inv = 1.0f / lrun[j];
        const int s = qbase + wv*16 + (lane >> 4)*4 + j;
        #pragma unroll
        for (int fn = 0; fn < 4; ++fn) {
            const int d = fn*16 + (lane & 15);
            ctx[((size_t)(s*BSZ + b))*EMB + h*DH + d] = f2bf(o[fn][j] * inv);
        }
    }
}

extern "C" void kernel_launch(void* const* d_in, const int* in_sizes, int n_in,
                              void* d_out, int out_size, void* d_ws, size_t ws_size,
                              hipStream_t stream) {
    const float* x    = (const float*)d_in[0];
    const float* mask = (const float*)d_in[1];
    const float* w_q  = (const float*)d_in[2];
    const float* w_k  = (const float*)d_in[3];
    const float* w_v  = (const float*)d_in[4];
    const float* w_o  = (const float*)d_in[5];
    const float* b_o  = (const float*)d_in[6];

    char* ws = (char*)d_ws;
    u16* xb  = (u16*)(ws);                        // 16 MB
    u16* wT  = (u16*)(ws + ((size_t)16 << 20));   // 8 MB (q,k,v,o transposed bf16)
    u16* qh  = (u16*)(ws + ((size_t)24 << 20));   // 16 MB
    u16* kh  = (u16*)(ws + ((size_t)40 << 20));   // 16 MB
    u16* vh  = (u16*)(ws + ((size_t)56 << 20));   // 16 MB
    u16* ctx = (u16*)(ws + ((size_t)72 << 20));   // 16 MB  (total 88 MB)
    float* outp = (float*)d_out;

    cvt_x_k<<<4096, 256, 0, stream>>>(x, xb);
    cvt_w_k<<<2048, 256, 0, stream>>>(w_q, w_k, w_v, w_o, wT);
    gemm_bt<0><<<dim3(8, 64, 3), 256, 0, stream>>>(xb, wT, x, nullptr, qh, kh, vh, nullptr);
    attn_k<<<dim3(16, 128), 256, 0, stream>>>(qh, kh, vh, mask, ctx);
    gemm_bt<1><<<dim3(8, 64, 1), 256, 0, stream>>>(ctx, wT + (size_t)3*1048576, nullptr, b_o,
                                                   nullptr, nullptr, nullptr, outp);
}